// Round 6
// baseline (1339.313 us; speedup 1.0000x reference)
//
#include <hip/hip_runtime.h>
#include <hip/hip_fp16.h>

// LinearCDE chunked parallel scan, MFMA edition, adaptive workspace.
//   y_t = y_{t-1} + A_t y_{t-1} + b_t;  A_t = reshape(inp_t @ Wa^T, [H,H])
//   inp_t = [dt, X[:,t]*dt];  b_t = inp_t @ Wb^T;  y_0 = X[:,0] @ Wi^T + bi
// R6: barrier-free compose. R5's 80us compose = 2400 cyc/step: two
// __syncthreads per step each force s_waitcnt vmcnt(0), draining the A
// prefetch -> full memory latency per step. Now each WAVE owns a 128x16
// column slab of M (8 C-tiles in regs + private LDS mirror read only by
// itself) -> no barriers at all in the 32-step loop; A-frags straight from
// global (9 waves/chunk share the 32 KB/step via L1/L2, mod-8 XCD swizzle).
// v-chain on a dedicated wave (colblk 4). Also: slices interleave
// amat->compose->chainscan_part->emit so emit reuses the resident A slice
// (no amat recompute).

typedef _Float16 h8 __attribute__((ext_vector_type(8)));
typedef float v4f __attribute__((ext_vector_type(4)));
typedef unsigned int uint;

constexpr int B_ = 8, S_ = 2048, D_ = 64, H_ = 128;
constexpr int T_ = S_ - 1;              // 2047
constexpr int KD = D_ + 1;              // 65
constexpr float DTC = 1.0f / 2047.0f;
constexpr int L_ = 32;                  // chunk length
constexpr int NC = 64;                  // chunks (last has 31 steps)

// ---------------- prep: Wa16B swizzle + Wa0 ----------------
__global__ __launch_bounds__(256) void k_prep_wa(const float* __restrict__ Wa,
                                                 _Float16* __restrict__ Wa16B,
                                                 float* __restrict__ Wa0) {
  int idx = blockIdx.x * 256 + threadIdx.x;     // 16384*64 exact
  int r = idx >> 6, kk = idx & 63;
  int rt = r >> 4, n = r & 15;
  int kb = kk >> 5, q = (kk >> 3) & 3, jj = kk & 7;
  float v = Wa[(size_t)r * KD + 1 + kk];
  Wa16B[((((size_t)rt * 2 + kb) * 4 + q) * 16 + n) * 8 + jj] = (_Float16)v;
  if (kk == 0) Wa0[r] = Wa[(size_t)r * KD];
}

__global__ __launch_bounds__(256) void k_prep_x(const float* __restrict__ X,
                                                _Float16* __restrict__ Xs16) {
  int idx = blockIdx.x * 256 + threadIdx.x;     // 16376*64 exact
  int bt = idx >> 6, d = idx & 63;
  int b = bt / T_, s = bt - b * T_;
  Xs16[(size_t)bt * 64 + d] = (_Float16)(X[((size_t)b * S_ + s + 1) * D_ + d] * DTC);
}

// ---------------- y0 ----------------
__global__ __launch_bounds__(128) void k_y0(const float* __restrict__ X,
                                            const float* __restrict__ Wi,
                                            const float* __restrict__ bi,
                                            float* __restrict__ out,
                                            float* __restrict__ ybound) {
  int b = blockIdx.x, h = threadIdx.x;
  __shared__ float xs[D_];
  if (h < D_) xs[h] = X[(size_t)b * S_ * D_ + h];
  __syncthreads();
  float acc = bi[h];
  const float* wr = Wi + h * D_;
#pragma unroll 8
  for (int d = 0; d < D_; d++) acc += xs[d] * wr[d];
  out[(size_t)b * S_ * H_ + h] = acc;
  if (ybound) ybound[(size_t)(b * NC + 0) * H_ + h] = acc;
}

// ---------------- Bs ----------------
__global__ __launch_bounds__(256) void k_bs(const float* __restrict__ X,
                                            const float* __restrict__ Wb,
                                            float* __restrict__ Bs) {
  __shared__ float wb_s[H_ * KD];
  __shared__ float xs[16][D_ + 4];
  int tid = threadIdx.x;
  int bt0 = blockIdx.x * 16;
  for (int i = tid; i < H_ * KD; i += 256) wb_s[i] = Wb[i];
  for (int i = tid; i < 16 * D_; i += 256) {
    int sl = i >> 6, d = i & 63;
    int btg = bt0 + sl;
    float v = 0.f;
    if (btg < B_ * T_) {
      int b = btg / T_, s = btg - b * T_;
      v = X[((size_t)b * S_ + s + 1) * D_ + d] * DTC;
    }
    xs[sl][d] = v;
  }
  __syncthreads();
  int h = tid & 127, sh = tid >> 7;
  const float* wrow = &wb_s[h * KD];
  for (int u = 0; u < 8; u++) {
    int sl = sh * 8 + u;
    int btg = bt0 + sl;
    if (btg >= B_ * T_) break;
    float acc = wrow[0] * DTC;
#pragma unroll 8
    for (int d = 0; d < D_; d++) acc += xs[sl][d] * wrow[1 + d];
    Bs[(size_t)btg * H_ + h] = acc;
  }
}

// ---------------- k_amat (MFMA): A slice rows ----------------
// grid (4*SC, 128). Block tile: 64 slice-rows x 128 cols, K=64.
__global__ __launch_bounds__(256) void k_amat(const _Float16* __restrict__ Xs16,
                                              const _Float16* __restrict__ Wa16B,
                                              const float* __restrict__ Wa0,
                                              _Float16* __restrict__ A_sl,
                                              int c0, int scShift) {
  __shared__ _Float16 sb[64 * 136];
  int tid = threadIdx.x;
  int w = tid >> 6, lane = tid & 63;
  int n = lane & 15, q = lane >> 4;          // n = m for A-op
  int rowbase = blockIdx.x * 64;
  int colbase = blockIdx.y * 128;
  int SCm = (1 << scShift) * 32 - 1;

  h8 af[4][2];
#pragma unroll
  for (int rt = 0; rt < 4; rt++) {
    int sidx = rowbase + rt * 16 + n;
    int b = sidx >> (scShift + 5);
    int rem = sidx & SCm;
    int cc = rem >> 5, l = rem & 31;
    int s = (c0 + cc) * 32 + l;
    if (s >= T_) s = T_ - 1;
    size_t btg = (size_t)b * T_ + s;
#pragma unroll
    for (int kb = 0; kb < 2; kb++)
      af[rt][kb] = *(const h8*)(Xs16 + btg * 64 + kb * 32 + q * 8);
  }
  h8 bf[2][2];
  float w0[2];
#pragma unroll
  for (int ctl = 0; ctl < 2; ctl++) {
    int ct_g = blockIdx.y * 8 + w * 2 + ctl;
#pragma unroll
    for (int kb = 0; kb < 2; kb++)
      bf[ctl][kb] = *(const h8*)(Wa16B + ((((size_t)ct_g * 2 + kb) * 4 + q) * 16 + n) * 8);
    w0[ctl] = Wa0[ct_g * 16 + n];
  }
#pragma unroll
  for (int ctl = 0; ctl < 2; ctl++) {
    float binit = DTC * w0[ctl];
#pragma unroll
    for (int rt = 0; rt < 4; rt++) {
      v4f a;
      a[0] = binit; a[1] = binit; a[2] = binit; a[3] = binit;
#pragma unroll
      for (int kb = 0; kb < 2; kb++)
        a = __builtin_amdgcn_mfma_f32_16x16x32_f16(af[rt][kb], bf[ctl][kb], a, 0, 0, 0);
      int col_l = (w * 2 + ctl) * 16 + n;
#pragma unroll
      for (int reg = 0; reg < 4; reg++) {
        int row_l = rt * 16 + q * 4 + reg;
        sb[row_l * 136 + col_l] = (_Float16)a[reg];
      }
    }
  }
  __syncthreads();
#pragma unroll
  for (int it = 0; it < 4; it++) {
    int idx = tid + it * 256;
    int rowl = idx >> 4, chunk = idx & 15;
    uint4 val = *(const uint4*)&sb[rowl * 136 + chunk * 8];
    size_t sidx = rowbase + rowl;
    *(uint4*)(A_sl + sidx * 16384 + colbase + chunk * 8) = val;
  }
}

// ---------------- k_compose (R6: barrier-free, wave-owned slabs) ----------
// grid = 5 * chunks, block = 128 (2 waves). chunk = bx & (chunks-1);
// colblk = bx >> (3+scShift). colblk 0..3: two waves, each owns a 128x16
// column slab (cols colblk*32 + w*16 ..). colblk 4: wave 0 runs the v-chain.
// All chunk siblings are congruent mod 8 (chunks is a multiple of 8) -> same
// XCD under round-robin -> shared L2 for the per-step 32 KB A reads.
__global__ __launch_bounds__(128) void k_compose(const _Float16* __restrict__ A_sl,
                                                 const float* __restrict__ Bs,
                                                 _Float16* __restrict__ Mc,
                                                 float* __restrict__ vc,
                                                 int c0, int scShift) {
  __shared__ _Float16 ex[2 * 16 * 136];   // per-wave slab mirror, col-major s136
  __shared__ float v32[128];
  int tid = threadIdx.x;
  int w = tid >> 6, lane = tid & 63;
  int n = lane & 15, q = lane >> 4;
  int chunks = B_ << scShift;
  int chunk = blockIdx.x & (chunks - 1);
  int colblk = blockIdx.x >> (3 + scShift);
  int SC = 1 << scShift;
  int b = chunk >> scShift;
  int c = c0 + (chunk & (SC - 1));
  int sbase = c * L_;
  int nsteps = min(L_, T_ - sbase);
  size_t Abase = (size_t)chunk * L_ * 16384;

  if (colblk == 4) {
    // ---- v-chain wave (wave 0 only) ----
    if (w == 1) return;
    v32[lane] = 0.f; v32[lane + 64] = 0.f;
    for (int l = 0; l < nsteps; l++) {
      const _Float16* Ag = A_sl + Abase + (size_t)l * 16384;
      h8 af[8][4];
#pragma unroll
      for (int mi = 0; mi < 8; mi++)
#pragma unroll
        for (int kb = 0; kb < 4; kb++)
          af[mi][kb] = *(const h8*)(Ag + (mi * 16 + n) * 128 + kb * 32 + q * 8);
      float vk[4][8];
#pragma unroll
      for (int kb = 0; kb < 4; kb++) {
        float4 p0 = *(const float4*)&v32[kb * 32 + q * 8];
        float4 p1 = *(const float4*)&v32[kb * 32 + q * 8 + 4];
        vk[kb][0] = p0.x; vk[kb][1] = p0.y; vk[kb][2] = p0.z; vk[kb][3] = p0.w;
        vk[kb][4] = p1.x; vk[kb][5] = p1.y; vk[kb][6] = p1.z; vk[kb][7] = p1.w;
      }
      float dv[8];
#pragma unroll
      for (int mi = 0; mi < 8; mi++) {
        float s = 0.f;
#pragma unroll
        for (int kb = 0; kb < 4; kb++)
#pragma unroll
          for (int jj = 0; jj < 8; jj++) s += (float)af[mi][kb][jj] * vk[kb][jj];
        s += __shfl_xor(s, 16);
        s += __shfl_xor(s, 32);
        dv[mi] = s;
      }
      size_t bt = (size_t)b * T_ + sbase + l;
      float vold[8], bs[8];
#pragma unroll
      for (int mi = 0; mi < 8; mi++) {
        vold[mi] = v32[mi * 16 + n];
        bs[mi] = Bs[bt * 128 + mi * 16 + n];
      }
      if (q == 0) {
#pragma unroll
        for (int mi = 0; mi < 8; mi++) v32[mi * 16 + n] = vold[mi] + dv[mi] + bs[mi];
      }
    }
    vc[(size_t)(b * NC + c) * 128 + lane] = v32[lane];
    vc[(size_t)(b * NC + c) * 128 + 64 + lane] = v32[64 + lane];
    return;
  }

  // ---- M-slab wave: cols gc0..gc0+15 ----
  int gc0 = colblk * 32 + w * 16;
  _Float16* myex = ex + w * (16 * 136);
  v4f acc[8];
#pragma unroll
  for (int mi = 0; mi < 8; mi++) {
    int row0 = mi * 16 + q * 4;
    union { _Float16 h[4]; uint2 u; } pk;
#pragma unroll
    for (int reg = 0; reg < 4; reg++) {
      float vv = (row0 + reg == gc0 + n) ? 1.f : 0.f;
      acc[mi][reg] = vv;
      pk.h[reg] = (_Float16)vv;
    }
    *(uint2*)&myex[n * 136 + row0] = pk.u;
  }

  for (int l = 0; l < nsteps; l++) {
    const _Float16* Ag = A_sl + Abase + (size_t)l * 16384;
    h8 af[8][4];
#pragma unroll
    for (int mi = 0; mi < 8; mi++)
#pragma unroll
      for (int kb = 0; kb < 4; kb++)
        af[mi][kb] = *(const h8*)(Ag + (mi * 16 + n) * 128 + kb * 32 + q * 8);
    h8 bfr[4];
#pragma unroll
    for (int kb = 0; kb < 4; kb++)
      bfr[kb] = *(const h8*)&myex[n * 136 + kb * 32 + q * 8];
#pragma unroll
    for (int mi = 0; mi < 8; mi++)
#pragma unroll
      for (int kb = 0; kb < 4; kb++)
        acc[mi] = __builtin_amdgcn_mfma_f32_16x16x32_f16(af[mi][kb], bfr[kb], acc[mi], 0, 0, 0);
    // refresh own mirror (wave-local; no barrier anywhere)
#pragma unroll
    for (int mi = 0; mi < 8; mi++) {
      union { _Float16 h[4]; uint2 u; } pk;
#pragma unroll
      for (int reg = 0; reg < 4; reg++) pk.h[reg] = (_Float16)acc[mi][reg];
      *(uint2*)&myex[n * 136 + mi * 16 + q * 4] = pk.u;
    }
  }
  // epilogue: Mc16 = M - I, col-major [col*128+row]
  _Float16* mcb = Mc + (size_t)(b * NC + c) * 16384;
#pragma unroll
  for (int mi = 0; mi < 8; mi++) {
    int row0 = mi * 16 + q * 4;
    union { _Float16 h[4]; uint2 u; } pk;
#pragma unroll
    for (int reg = 0; reg < 4; reg++) {
      float vv = acc[mi][reg];
      if (row0 + reg == gc0 + n) vv -= 1.f;
      pk.h[reg] = (_Float16)vv;
    }
    *(uint2*)(mcb + (size_t)(gc0 + n) * 128 + row0) = pk.u;
  }
}

// ---------------- k_chainscan (range [c0, c0+nc)) ----------------
__global__ __launch_bounds__(256) void k_chainscan(const _Float16* __restrict__ Mc,
                                                   const float* __restrict__ vc,
                                                   float* __restrict__ yb,
                                                   int c0, int nc) {
  int b = blockIdx.x, tid = threadIdx.x;
  int i2 = (tid & 63) * 2;      // row pair
  int jb = tid >> 6;            // column block (4 x 32)
  __shared__ float ybuf[128];
  __shared__ float part[4][128];
  if (tid < 128) ybuf[tid] = yb[(size_t)(b * NC + c0) * 128 + tid];
  __syncthreads();

  uint bufA[32], bufB[32];
  float vvA, vvB;

#define LOADC(buf, vv, cch)                                                          \
  {                                                                                  \
    const uint* p = (const uint*)(Mc + (size_t)(b * NC + (cch)) * 16384);            \
    _Pragma("unroll")                                                                \
    for (int j = 0; j < 32; j++) buf[j] = p[(size_t)(jb * 32 + j) * 64 + (i2 >> 1)]; \
    vv = vc[(size_t)(b * NC + (cch)) * 128 + (tid & 127)];                           \
  }

#define STEPC(buf, vv, cch)                                                          \
  {                                                                                  \
    float s0 = 0.f, s1 = 0.f;                                                        \
    _Pragma("unroll")                                                                \
    for (int j = 0; j < 32; j++) {                                                   \
      union { uint u; _Float16 h[2]; } e; e.u = buf[j];                              \
      float yj = ybuf[jb * 32 + j];                                                  \
      s0 += (float)e.h[0] * yj; s1 += (float)e.h[1] * yj;                            \
    }                                                                                \
    part[jb][i2] = s0; part[jb][i2 + 1] = s1;                                        \
    __syncthreads();                                                                 \
    if (tid < 128) {                                                                 \
      float yn = ybuf[tid] + vv + part[0][tid] + part[1][tid] + part[2][tid] + part[3][tid]; \
      if ((cch) < NC - 1) yb[(size_t)(b * NC + (cch) + 1) * 128 + tid] = yn;         \
      ybuf[tid] = yn;                                                                \
    }                                                                                \
    __syncthreads();                                                                 \
  }

  int cend = c0 + nc;
  LOADC(bufA, vvA, c0);
  int c = c0;
  for (; c + 1 < cend; c += 2) {
    LOADC(bufB, vvB, c + 1);
    STEPC(bufA, vvA, c);
    if (c + 2 < cend) LOADC(bufA, vvA, c + 2);
    STEPC(bufB, vvB, c + 1);
  }
  if (c < cend) STEPC(bufA, vvA, c);
#undef LOADC
#undef STEPC
}

// ---------------- k_emit ----------------
__global__ __launch_bounds__(256) void k_emit(const _Float16* __restrict__ A_sl,
                                              const float* __restrict__ Bs,
                                              const float* __restrict__ yb,
                                              float* __restrict__ out,
                                              int c0, int scShift) {
  int tid = threadIdx.x;
  int SC = 1 << scShift;
  int b = blockIdx.x >> scShift;
  int cc = blockIdx.x & (SC - 1);
  int c = c0 + cc;
  int i = tid >> 1, hh = tid & 1;
  __shared__ float ybuf[128];
  __shared__ float red[128];
  if (tid < 128) ybuf[tid] = yb[(size_t)(b * NC + c) * 128 + tid];
  __syncthreads();
  int nst = min(L_, T_ - c * L_);
  size_t sidx0 = (size_t)blockIdx.x * L_;
  size_t btb = (size_t)b * T_ + c * L_;

  uint4 arA[8], arB[8];
  float bsA, bsB;

#define LOADR(ar, bsv, l)                                                            \
  {                                                                                  \
    const uint4* p = (const uint4*)(A_sl + (sidx0 + (l)) * 16384 + i * 128 + hh * 64); \
    _Pragma("unroll")                                                                \
    for (int u = 0; u < 8; u++) ar[u] = p[u];                                        \
    bsv = Bs[(btb + (l)) * 128 + i];                                                 \
  }

#define STEPE(ar, bsv, l)                                                            \
  {                                                                                  \
    float pt = 0.f;                                                                  \
    _Pragma("unroll")                                                                \
    for (int u = 0; u < 8; u++) {                                                    \
      union { uint4 v; _Float16 h[8]; } wv; wv.v = ar[u];                            \
      _Pragma("unroll")                                                              \
      for (int k = 0; k < 8; k++) pt += (float)wv.h[k] * ybuf[hh * 64 + u * 8 + k];  \
    }                                                                                \
    if (hh) red[i] = pt;                                                             \
    __syncthreads();                                                                 \
    if (!hh) {                                                                       \
      float yn = ybuf[i] + pt + red[i] + bsv;                                        \
      out[((size_t)b * S_ + (size_t)(c * L_ + (l) + 1)) * 128 + i] = yn;             \
      ybuf[i] = yn;                                                                  \
    }                                                                                \
    __syncthreads();                                                                 \
  }

  LOADR(arA, bsA, 0);
  for (int l = 0; l < nst; l += 2) {
    if (l + 1 < nst) LOADR(arB, bsB, l + 1);
    STEPE(arA, bsA, l);
    if (l + 2 < nst) LOADR(arA, bsA, l + 2);
    if (l + 1 < nst) STEPE(arB, bsB, l + 1);
  }
#undef LOADR
#undef STEPE
}

// ---------------- fallback: plain sequential ----------------
__global__ __launch_bounds__(256) void k_seq(const float* __restrict__ X,
                                             const float* __restrict__ Wa,
                                             const float* __restrict__ Wb,
                                             float* __restrict__ out) {
  int b = blockIdx.x, tid = threadIdx.x;
  int i = tid >> 1, hh = tid & 1;
  __shared__ float y[H_], red[H_], xs[D_], bts[H_];
  if (tid < H_) y[tid] = out[(size_t)b * S_ * H_ + tid];
  __syncthreads();
  for (int t = 1; t < S_; t++) {
    if (tid < D_) xs[tid] = X[((size_t)b * S_ + t) * D_ + tid] * DTC;
    __syncthreads();
    if (tid < H_) {
      const float* wr = Wb + tid * KD;
      float acc = wr[0] * DTC;
#pragma unroll 8
      for (int d = 0; d < D_; d++) acc += xs[d] * wr[1 + d];
      bts[tid] = acc;
    }
    float part = 0.f;
    const float* yhalf = &y[hh * 64];
    for (int j = 0; j < 64; j++) {
      const float* wr = Wa + ((size_t)(i * H_) + hh * 64 + j) * KD;
      float a = wr[0] * DTC;
#pragma unroll 8
      for (int d = 0; d < D_; d++) a += xs[d] * wr[1 + d];
      part += a * yhalf[j];
    }
    if (hh) red[i] = part;
    __syncthreads();
    if (!hh) {
      float yn = y[i] + part + red[i] + bts[i];
      out[((size_t)b * S_ + t) * H_ + i] = yn;
      y[i] = yn;
    }
    __syncthreads();
  }
}

extern "C" void kernel_launch(void* const* d_in, const int* in_sizes, int n_in,
                              void* d_out, int out_size, void* d_ws, size_t ws_size,
                              hipStream_t stream) {
  (void)in_sizes; (void)n_in; (void)out_size;
  const float* X  = (const float*)d_in[0];
  const float* Wi = (const float*)d_in[1];
  const float* bi = (const float*)d_in[2];
  const float* Wa = (const float*)d_in[3];
  const float* Wb = (const float*)d_in[4];
  float* out = (float*)d_out;
  char* ws = (char*)d_ws;

  size_t off = 0;
  auto alloc = [&](size_t bytes) { size_t o = off; off = (off + bytes + 255) & ~(size_t)255; return o; };
  size_t oMc  = alloc((size_t)B_ * NC * 16384 * 2);     // 16.78 MB
  size_t oBs  = alloc((size_t)B_ * T_ * 128 * 4);       //  8.38 MB
  size_t oVc  = alloc((size_t)B_ * NC * 128 * 4);
  size_t oYb  = alloc((size_t)B_ * NC * 128 * 4);
  size_t oWaB = alloc((size_t)64 * 16384 * 2);          //  2.10 MB
  size_t oWa0 = alloc((size_t)16384 * 4);
  size_t oXs  = alloc((size_t)B_ * T_ * 64 * 2);        //  2.10 MB
  size_t persistent = off;
  const size_t BPC = (size_t)B_ * L_ * 16384 * 2;       // 8.39 MB per chunk-column

  int SC = 0;
  if (ws_size > persistent) {
    size_t avail = ws_size - persistent;
    SC = 64;
    while (SC > 0 && (size_t)SC * BPC > avail) SC >>= 1;
  }
  if (SC < 1) {
    k_y0<<<B_, 128, 0, stream>>>(X, Wi, bi, out, nullptr);
    k_seq<<<B_, 256, 0, stream>>>(X, Wa, Wb, out);
    return;
  }
  int scShift = __builtin_ctz(SC);

  _Float16* Mc   = (_Float16*)(ws + oMc);
  float*    Bs   = (float*)(ws + oBs);
  float*    vc   = (float*)(ws + oVc);
  float*    yb   = (float*)(ws + oYb);
  _Float16* Wa16B = (_Float16*)(ws + oWaB);
  float*    Wa0  = (float*)(ws + oWa0);
  _Float16* Xs16 = (_Float16*)(ws + oXs);
  _Float16* A_sl = (_Float16*)(ws + persistent);

  k_prep_wa<<<4096, 256, 0, stream>>>(Wa, Wa16B, Wa0);
  k_prep_x<<<4094, 256, 0, stream>>>(X, Xs16);
  k_y0<<<B_, 128, 0, stream>>>(X, Wi, bi, out, yb);
  k_bs<<<(B_ * T_ + 15) / 16, 256, 0, stream>>>(X, Wb, Bs);

  int nslices = NC / SC;
  int chunks = B_ * SC;
  for (int si = 0; si < nslices; si++) {
    int c0 = si * SC;
    k_amat<<<dim3(4 * SC, 128), 256, 0, stream>>>(Xs16, Wa16B, Wa0, A_sl, c0, scShift);
    k_compose<<<5 * chunks, 128, 0, stream>>>(A_sl, Bs, Mc, vc, c0, scShift);
    k_chainscan<<<B_, 256, 0, stream>>>(Mc, vc, yb, c0, SC);
    k_emit<<<chunks, 256, 0, stream>>>(A_sl, Bs, yb, out, c0, scShift);
  }
}

// Round 7
// 830.322 us; speedup vs baseline: 1.6130x; 1.6130x over previous
//
#include <hip/hip_runtime.h>
#include <hip/hip_fp16.h>

// LinearCDE chunked parallel scan, MFMA edition, adaptive workspace.
//   y_t = y_{t-1} + A_t y_{t-1} + b_t;  A_t = reshape(inp_t @ Wa^T, [H,H])
//   inp_t = [dt, X[:,t]*dt];  b_t = inp_t @ Wb^T;  y_0 = X[:,0] @ Wi^T + bi
// R7: L=32 -> L=8 (NC=256). Evidence: R3 (64 blocks) and R5 (256 blocks)
// compose both ~80us => time = 32 x step-latency (~2400cyc), spatial
// parallelism irrelevant — pure latency chain. Fix: 4x more chunks ->
// 4 compose blocks/CU (TLP hides barrier/vmcnt stalls) and 8-step chains.
// Compose keeps R5's spill-free 4-wave structure. Mc/vc are slice-local
// (chainscan consumes per slice). Emit/amat gain the same parallelism.

typedef _Float16 h8 __attribute__((ext_vector_type(8)));
typedef float v4f __attribute__((ext_vector_type(4)));
typedef unsigned int uint;

constexpr int B_ = 8, S_ = 2048, D_ = 64, H_ = 128;
constexpr int T_ = S_ - 1;              // 2047
constexpr int KD = D_ + 1;              // 65
constexpr float DTC = 1.0f / 2047.0f;
constexpr int L_ = 8;                   // chunk length
constexpr int LSH = 3;                  // log2(L_)
constexpr int NC = 256;                 // chunks per batch (last has 7 steps)

// ---------------- prep: Wa16B swizzle + Wa0 ----------------
__global__ __launch_bounds__(256) void k_prep_wa(const float* __restrict__ Wa,
                                                 _Float16* __restrict__ Wa16B,
                                                 float* __restrict__ Wa0) {
  int idx = blockIdx.x * 256 + threadIdx.x;     // 16384*64 exact
  int r = idx >> 6, kk = idx & 63;
  int rt = r >> 4, n = r & 15;
  int kb = kk >> 5, q = (kk >> 3) & 3, jj = kk & 7;
  float v = Wa[(size_t)r * KD + 1 + kk];
  Wa16B[((((size_t)rt * 2 + kb) * 4 + q) * 16 + n) * 8 + jj] = (_Float16)v;
  if (kk == 0) Wa0[r] = Wa[(size_t)r * KD];
}

__global__ __launch_bounds__(256) void k_prep_x(const float* __restrict__ X,
                                                _Float16* __restrict__ Xs16) {
  int idx = blockIdx.x * 256 + threadIdx.x;     // 16376*64 exact
  int bt = idx >> 6, d = idx & 63;
  int b = bt / T_, s = bt - b * T_;
  Xs16[(size_t)bt * 64 + d] = (_Float16)(X[((size_t)b * S_ + s + 1) * D_ + d] * DTC);
}

// ---------------- y0 ----------------
__global__ __launch_bounds__(128) void k_y0(const float* __restrict__ X,
                                            const float* __restrict__ Wi,
                                            const float* __restrict__ bi,
                                            float* __restrict__ out,
                                            float* __restrict__ ybound) {
  int b = blockIdx.x, h = threadIdx.x;
  __shared__ float xs[D_];
  if (h < D_) xs[h] = X[(size_t)b * S_ * D_ + h];
  __syncthreads();
  float acc = bi[h];
  const float* wr = Wi + h * D_;
#pragma unroll 8
  for (int d = 0; d < D_; d++) acc += xs[d] * wr[d];
  out[(size_t)b * S_ * H_ + h] = acc;
  if (ybound) ybound[(size_t)(b * NC + 0) * H_ + h] = acc;
}

// ---------------- Bs ----------------
__global__ __launch_bounds__(256) void k_bs(const float* __restrict__ X,
                                            const float* __restrict__ Wb,
                                            float* __restrict__ Bs) {
  __shared__ float wb_s[H_ * KD];
  __shared__ float xs[16][D_ + 4];
  int tid = threadIdx.x;
  int bt0 = blockIdx.x * 16;
  for (int i = tid; i < H_ * KD; i += 256) wb_s[i] = Wb[i];
  for (int i = tid; i < 16 * D_; i += 256) {
    int sl = i >> 6, d = i & 63;
    int btg = bt0 + sl;
    float v = 0.f;
    if (btg < B_ * T_) {
      int b = btg / T_, s = btg - b * T_;
      v = X[((size_t)b * S_ + s + 1) * D_ + d] * DTC;
    }
    xs[sl][d] = v;
  }
  __syncthreads();
  int h = tid & 127, sh = tid >> 7;
  const float* wrow = &wb_s[h * KD];
  for (int u = 0; u < 8; u++) {
    int sl = sh * 8 + u;
    int btg = bt0 + sl;
    if (btg >= B_ * T_) break;
    float acc = wrow[0] * DTC;
#pragma unroll 8
    for (int d = 0; d < D_; d++) acc += xs[sl][d] * wrow[1 + d];
    Bs[(size_t)btg * H_ + h] = acc;
  }
}

// ---------------- k_amat (MFMA): A slice rows ----------------
// grid (B*SC*L/64, 128). Block tile: 64 slice-rows x 128 cols, K=64.
__global__ __launch_bounds__(256) void k_amat(const _Float16* __restrict__ Xs16,
                                              const _Float16* __restrict__ Wa16B,
                                              const float* __restrict__ Wa0,
                                              _Float16* __restrict__ A_sl,
                                              int c0, int scShift) {
  __shared__ _Float16 sb[64 * 136];
  int tid = threadIdx.x;
  int w = tid >> 6, lane = tid & 63;
  int n = lane & 15, q = lane >> 4;          // n = m for A-op
  int rowbase = blockIdx.x * 64;
  int colbase = blockIdx.y * 128;
  int SCm = ((1 << scShift) << LSH) - 1;

  h8 af[4][2];
#pragma unroll
  for (int rt = 0; rt < 4; rt++) {
    int sidx = rowbase + rt * 16 + n;
    int b = sidx >> (scShift + LSH);
    int rem = sidx & SCm;
    int cc = rem >> LSH, l = rem & (L_ - 1);
    int s = (c0 + cc) * L_ + l;
    if (s >= T_) s = T_ - 1;
    size_t btg = (size_t)b * T_ + s;
#pragma unroll
    for (int kb = 0; kb < 2; kb++)
      af[rt][kb] = *(const h8*)(Xs16 + btg * 64 + kb * 32 + q * 8);
  }
  h8 bf[2][2];
  float w0[2];
#pragma unroll
  for (int ctl = 0; ctl < 2; ctl++) {
    int ct_g = blockIdx.y * 8 + w * 2 + ctl;
#pragma unroll
    for (int kb = 0; kb < 2; kb++)
      bf[ctl][kb] = *(const h8*)(Wa16B + ((((size_t)ct_g * 2 + kb) * 4 + q) * 16 + n) * 8);
    w0[ctl] = Wa0[ct_g * 16 + n];
  }
#pragma unroll
  for (int ctl = 0; ctl < 2; ctl++) {
    float binit = DTC * w0[ctl];
#pragma unroll
    for (int rt = 0; rt < 4; rt++) {
      v4f a;
      a[0] = binit; a[1] = binit; a[2] = binit; a[3] = binit;
#pragma unroll
      for (int kb = 0; kb < 2; kb++)
        a = __builtin_amdgcn_mfma_f32_16x16x32_f16(af[rt][kb], bf[ctl][kb], a, 0, 0, 0);
      int col_l = (w * 2 + ctl) * 16 + n;
#pragma unroll
      for (int reg = 0; reg < 4; reg++) {
        int row_l = rt * 16 + q * 4 + reg;
        sb[row_l * 136 + col_l] = (_Float16)a[reg];
      }
    }
  }
  __syncthreads();
#pragma unroll
  for (int it = 0; it < 4; it++) {
    int idx = tid + it * 256;
    int rowl = idx >> 4, chunk = idx & 15;
    uint4 val = *(const uint4*)&sb[rowl * 136 + chunk * 8];
    size_t sidx = rowbase + rowl;
    *(uint4*)(A_sl + sidx * 16384 + colbase + chunk * 8) = val;
  }
}

// ---------------- k_compose (MFMA, column split, spill-free dbuf) ----------
// blocks = 4 * B * SC. chunk = (bx>>5)*8 + (bx&7); colblk = (bx>>3)&3 so the
// 4 colblks of a chunk are congruent mod 8 (same XCD under round-robin).
// Mc/vc are SLICE-LOCAL, indexed by linear chunk = b*SC + cc.
__global__ __launch_bounds__(256) void k_compose(const _Float16* __restrict__ A_sl,
                                                 const float* __restrict__ Bs,
                                                 _Float16* __restrict__ Mc,
                                                 float* __restrict__ vc,
                                                 int c0, int scShift) {
  __shared__ _Float16 Mt[32 * 136];    // this block's 32 cols, transposed
  __shared__ float v32[128];
  int tid = threadIdx.x;
  int w = tid >> 6, lane = tid & 63;
  int n = lane & 15, q = lane >> 4;
  int bx = blockIdx.x;
  int chunk = ((bx >> 5) << 3) + (bx & 7);   // linear chunk in dispatch
  int colblk = (bx >> 3) & 3;
  int SC = 1 << scShift;
  int b = chunk >> scShift;
  int cc = chunk & (SC - 1);
  int c = c0 + cc;

  v4f acc[2][2];
#pragma unroll
  for (int mi = 0; mi < 2; mi++) {
    int row0 = (2 * w + mi) * 16 + q * 4;
#pragma unroll
    for (int nj = 0; nj < 2; nj++) {
      int gcol = colblk * 32 + nj * 16 + n;
      union { _Float16 h[4]; uint2 u; } pk;
#pragma unroll
      for (int reg = 0; reg < 4; reg++) {
        float vv = (row0 + reg == gcol) ? 1.f : 0.f;
        acc[mi][nj][reg] = vv;
        pk.h[reg] = (_Float16)vv;
      }
      *(uint2*)&Mt[(nj * 16 + n) * 136 + row0] = pk.u;
    }
  }
  if (tid < 128) v32[tid] = 0.f;
  __syncthreads();

  int sbase = c * L_;
  int nsteps = min(L_, T_ - sbase);
  size_t Abase = (size_t)chunk * L_ * 16384;
  int r0 = 2 * w * 16 + (lane & 15);
  int r1 = r0 + 16;

  h8 afA[2][4], afB[2][4];   // named double buffers, constant indices only

#define LOADA(dst, l)                                                                \
  {                                                                                  \
    const _Float16* Ag = A_sl + Abase + (size_t)(l) * 16384;                         \
    _Pragma("unroll")                                                                \
    for (int mi = 0; mi < 2; mi++)                                                   \
      _Pragma("unroll")                                                              \
      for (int kb = 0; kb < 4; kb++)                                                 \
        dst[mi][kb] = *(const h8*)(Ag + ((2 * w + mi) * 16 + n) * 128 + kb * 32 + q * 8); \
  }

#define STEPA(af, l)                                                                 \
  {                                                                                  \
    _Pragma("unroll")                                                                \
    for (int nj = 0; nj < 2; nj++) {                                                 \
      h8 bfr[4];                                                                     \
      _Pragma("unroll")                                                              \
      for (int kb = 0; kb < 4; kb++)                                                 \
        bfr[kb] = *(const h8*)&Mt[(nj * 16 + n) * 136 + kb * 32 + q * 8];            \
      _Pragma("unroll")                                                              \
      for (int mi = 0; mi < 2; mi++)                                                 \
        _Pragma("unroll")                                                            \
        for (int kb = 0; kb < 4; kb++)                                               \
          acc[mi][nj] = __builtin_amdgcn_mfma_f32_16x16x32_f16(af[mi][kb], bfr[kb], acc[mi][nj], 0, 0, 0); \
    }                                                                                \
    float dv0 = 0.f, dv1 = 0.f, vold0 = 0.f, vold1 = 0.f, bs0 = 0.f, bs1 = 0.f;      \
    if (colblk == 0) {                                                               \
      _Pragma("unroll")                                                              \
      for (int kb = 0; kb < 4; kb++) {                                               \
        float4 p0 = *(const float4*)&v32[kb * 32 + q * 8];                           \
        float4 p1 = *(const float4*)&v32[kb * 32 + q * 8 + 4];                       \
        float vk[8] = {p0.x, p0.y, p0.z, p0.w, p1.x, p1.y, p1.z, p1.w};              \
        _Pragma("unroll")                                                            \
        for (int jj = 0; jj < 8; jj++) {                                             \
          dv0 += (float)af[0][kb][jj] * vk[jj];                                      \
          dv1 += (float)af[1][kb][jj] * vk[jj];                                      \
        }                                                                            \
      }                                                                              \
      dv0 += __shfl_xor(dv0, 16); dv0 += __shfl_xor(dv0, 32);                        \
      dv1 += __shfl_xor(dv1, 16); dv1 += __shfl_xor(dv1, 32);                        \
      vold0 = v32[r0]; vold1 = v32[r1];                                              \
      size_t bt = (size_t)b * T_ + sbase + (l);                                      \
      bs0 = Bs[bt * 128 + r0];                                                       \
      bs1 = Bs[bt * 128 + r1];                                                       \
    }                                                                                \
    __syncthreads();                                                                 \
    _Pragma("unroll")                                                                \
    for (int mi = 0; mi < 2; mi++) {                                                 \
      int row0 = (2 * w + mi) * 16 + q * 4;                                          \
      _Pragma("unroll")                                                              \
      for (int nj = 0; nj < 2; nj++) {                                               \
        union { _Float16 h[4]; uint2 u; } pk;                                        \
        _Pragma("unroll")                                                            \
        for (int reg = 0; reg < 4; reg++) pk.h[reg] = (_Float16)acc[mi][nj][reg];    \
        *(uint2*)&Mt[(nj * 16 + n) * 136 + row0] = pk.u;                             \
      }                                                                              \
    }                                                                                \
    if (colblk == 0 && q == 0) {                                                     \
      v32[r0] = vold0 + dv0 + bs0;                                                   \
      v32[r1] = vold1 + dv1 + bs1;                                                   \
    }                                                                                \
    __syncthreads();                                                                 \
  }

  LOADA(afA, 0);
  for (int l = 0; l < nsteps; l += 2) {
    if (l + 1 < nsteps) LOADA(afB, l + 1);
    STEPA(afA, l);
    if (l + 2 < nsteps) LOADA(afA, l + 2);
    if (l + 1 < nsteps) STEPA(afB, l + 1);
  }
#undef LOADA
#undef STEPA

  // epilogue: Mc16 = M - I (col-major), this block's 32 cols; vc by colblk 0
  _Float16* mcb = Mc + (size_t)chunk * 16384;
#pragma unroll
  for (int mi = 0; mi < 2; mi++) {
    int row0 = (2 * w + mi) * 16 + q * 4;
#pragma unroll
    for (int nj = 0; nj < 2; nj++) {
      int gcol = colblk * 32 + nj * 16 + n;
      union { _Float16 h[4]; uint2 u; } pk;
#pragma unroll
      for (int reg = 0; reg < 4; reg++) {
        float vv = acc[mi][nj][reg];
        if (row0 + reg == gcol) vv -= 1.f;
        pk.h[reg] = (_Float16)vv;
      }
      *(uint2*)(mcb + (size_t)gcol * 128 + row0) = pk.u;
    }
  }
  if (colblk == 0 && tid < 128) vc[(size_t)chunk * 128 + tid] = v32[tid];
}

// ---------------- k_chainscan (slice-local Mc/vc, global yb) ----------------
__global__ __launch_bounds__(256) void k_chainscan(const _Float16* __restrict__ Mc,
                                                   const float* __restrict__ vc,
                                                   float* __restrict__ yb,
                                                   int c0, int scShift) {
  int b = blockIdx.x, tid = threadIdx.x;
  int SC = 1 << scShift;
  int i2 = (tid & 63) * 2;      // row pair
  int jb = tid >> 6;            // column block (4 x 32)
  __shared__ float ybuf[128];
  __shared__ float part[4][128];
  if (tid < 128) ybuf[tid] = yb[(size_t)(b * NC + c0) * 128 + tid];
  __syncthreads();

  uint bufA[32], bufB[32];
  float vvA, vvB;

#define LOADC(buf, vv, lc)                                                           \
  {                                                                                  \
    const uint* p = (const uint*)(Mc + (size_t)((b << scShift) | (lc)) * 16384);     \
    _Pragma("unroll")                                                                \
    for (int j = 0; j < 32; j++) buf[j] = p[(size_t)(jb * 32 + j) * 64 + (i2 >> 1)]; \
    vv = vc[(size_t)((b << scShift) | (lc)) * 128 + (tid & 127)];                    \
  }

#define STEPC(buf, vv, lc)                                                           \
  {                                                                                  \
    float s0 = 0.f, s1 = 0.f;                                                        \
    _Pragma("unroll")                                                                \
    for (int j = 0; j < 32; j++) {                                                   \
      union { uint u; _Float16 h[2]; } e; e.u = buf[j];                              \
      float yj = ybuf[jb * 32 + j];                                                  \
      s0 += (float)e.h[0] * yj; s1 += (float)e.h[1] * yj;                            \
    }                                                                                \
    part[jb][i2] = s0; part[jb][i2 + 1] = s1;                                        \
    __syncthreads();                                                                 \
    if (tid < 128) {                                                                 \
      float yn = ybuf[tid] + vv + part[0][tid] + part[1][tid] + part[2][tid] + part[3][tid]; \
      int cg = c0 + (lc);                                                            \
      if (cg < NC - 1) yb[(size_t)(b * NC + cg + 1) * 128 + tid] = yn;               \
      ybuf[tid] = yn;                                                                \
    }                                                                                \
    __syncthreads();                                                                 \
  }

  LOADC(bufA, vvA, 0);
  int lc = 0;
  for (; lc + 1 < SC; lc += 2) {
    LOADC(bufB, vvB, lc + 1);
    STEPC(bufA, vvA, lc);
    if (lc + 2 < SC) LOADC(bufA, vvA, lc + 2);
    STEPC(bufB, vvB, lc + 1);
  }
  if (lc < SC) STEPC(bufA, vvA, lc);
#undef LOADC
#undef STEPC
}

// ---------------- k_emit ----------------
__global__ __launch_bounds__(256) void k_emit(const _Float16* __restrict__ A_sl,
                                              const float* __restrict__ Bs,
                                              const float* __restrict__ yb,
                                              float* __restrict__ out,
                                              int c0, int scShift) {
  int tid = threadIdx.x;
  int SC = 1 << scShift;
  int b = blockIdx.x >> scShift;
  int cc = blockIdx.x & (SC - 1);
  int c = c0 + cc;
  int i = tid >> 1, hh = tid & 1;
  __shared__ float ybuf[128];
  __shared__ float red[128];
  if (tid < 128) ybuf[tid] = yb[(size_t)(b * NC + c) * 128 + tid];
  __syncthreads();
  int nst = min(L_, T_ - c * L_);
  size_t sidx0 = (size_t)blockIdx.x * L_;
  size_t btb = (size_t)b * T_ + c * L_;

  uint4 arA[8], arB[8];
  float bsA, bsB;

#define LOADR(ar, bsv, l)                                                            \
  {                                                                                  \
    const uint4* p = (const uint4*)(A_sl + (sidx0 + (l)) * 16384 + i * 128 + hh * 64); \
    _Pragma("unroll")                                                                \
    for (int u = 0; u < 8; u++) ar[u] = p[u];                                        \
    bsv = Bs[(btb + (l)) * 128 + i];                                                 \
  }

#define STEPE(ar, bsv, l)                                                            \
  {                                                                                  \
    float pt = 0.f;                                                                  \
    _Pragma("unroll")                                                                \
    for (int u = 0; u < 8; u++) {                                                    \
      union { uint4 v; _Float16 h[8]; } wv; wv.v = ar[u];                            \
      _Pragma("unroll")                                                              \
      for (int k = 0; k < 8; k++) pt += (float)wv.h[k] * ybuf[hh * 64 + u * 8 + k];  \
    }                                                                                \
    if (hh) red[i] = pt;                                                             \
    __syncthreads();                                                                 \
    if (!hh) {                                                                       \
      float yn = ybuf[i] + pt + red[i] + bsv;                                        \
      out[((size_t)b * S_ + (size_t)(c * L_ + (l) + 1)) * 128 + i] = yn;             \
      ybuf[i] = yn;                                                                  \
    }                                                                                \
    __syncthreads();                                                                 \
  }

  LOADR(arA, bsA, 0);
  for (int l = 0; l < nst; l += 2) {
    if (l + 1 < nst) LOADR(arB, bsB, l + 1);
    STEPE(arA, bsA, l);
    if (l + 2 < nst) LOADR(arA, bsA, l + 2);
    if (l + 1 < nst) STEPE(arB, bsB, l + 1);
  }
#undef LOADR
#undef STEPE
}

// ---------------- fallback: plain sequential ----------------
__global__ __launch_bounds__(256) void k_seq(const float* __restrict__ X,
                                             const float* __restrict__ Wa,
                                             const float* __restrict__ Wb,
                                             float* __restrict__ out) {
  int b = blockIdx.x, tid = threadIdx.x;
  int i = tid >> 1, hh = tid & 1;
  __shared__ float y[H_], red[H_], xs[D_], bts[H_];
  if (tid < H_) y[tid] = out[(size_t)b * S_ * H_ + tid];
  __syncthreads();
  for (int t = 1; t < S_; t++) {
    if (tid < D_) xs[tid] = X[((size_t)b * S_ + t) * D_ + tid] * DTC;
    __syncthreads();
    if (tid < H_) {
      const float* wr = Wb + tid * KD;
      float acc = wr[0] * DTC;
#pragma unroll 8
      for (int d = 0; d < D_; d++) acc += xs[d] * wr[1 + d];
      bts[tid] = acc;
    }
    float part = 0.f;
    const float* yhalf = &y[hh * 64];
    for (int j = 0; j < 64; j++) {
      const float* wr = Wa + ((size_t)(i * H_) + hh * 64 + j) * KD;
      float a = wr[0] * DTC;
#pragma unroll 8
      for (int d = 0; d < D_; d++) a += xs[d] * wr[1 + d];
      part += a * yhalf[j];
    }
    if (hh) red[i] = part;
    __syncthreads();
    if (!hh) {
      float yn = y[i] + part + red[i] + bts[i];
      out[((size_t)b * S_ + t) * H_ + i] = yn;
      y[i] = yn;
    }
    __syncthreads();
  }
}

extern "C" void kernel_launch(void* const* d_in, const int* in_sizes, int n_in,
                              void* d_out, int out_size, void* d_ws, size_t ws_size,
                              hipStream_t stream) {
  (void)in_sizes; (void)n_in; (void)out_size;
  const float* X  = (const float*)d_in[0];
  const float* Wi = (const float*)d_in[1];
  const float* bi = (const float*)d_in[2];
  const float* Wa = (const float*)d_in[3];
  const float* Wb = (const float*)d_in[4];
  float* out = (float*)d_out;
  char* ws = (char*)d_ws;

  size_t off = 0;
  auto alloc = [&](size_t bytes) { size_t o = off; off = (off + bytes + 255) & ~(size_t)255; return o; };
  size_t oBs  = alloc((size_t)B_ * T_ * 128 * 4);       //  8.38 MB
  size_t oYb  = alloc((size_t)B_ * NC * 128 * 4);       //  1.05 MB
  size_t oWaB = alloc((size_t)64 * 16384 * 2);          //  2.10 MB
  size_t oWa0 = alloc((size_t)16384 * 4);
  size_t oXs  = alloc((size_t)B_ * T_ * 64 * 2);        //  2.10 MB
  size_t fixed = off;

  // per chunk-column slice cost: A + Mc + vc
  const size_t BPC   = (size_t)B_ * L_ * 16384 * 2;     // 2.10 MB
  const size_t MCPC  = (size_t)B_ * 16384 * 2;          // 0.26 MB
  const size_t VCPC  = (size_t)B_ * 128 * 4;            // 4 KB
  const size_t PER_SC = BPC + MCPC + VCPC + 3 * 256;

  int SC = 0;
  if (ws_size > fixed) {
    size_t avail = ws_size - fixed;
    SC = 64;
    while (SC > 0 && (size_t)SC * PER_SC > avail) SC >>= 1;
  }
  if (SC < 1) {
    k_y0<<<B_, 128, 0, stream>>>(X, Wi, bi, out, nullptr);
    k_seq<<<B_, 256, 0, stream>>>(X, Wa, Wb, out);
    return;
  }
  int scShift = __builtin_ctz(SC);

  size_t oMc = alloc((size_t)SC * MCPC);
  size_t oVc = alloc((size_t)SC * VCPC);
  size_t oA  = alloc((size_t)SC * BPC);

  float*    Bs    = (float*)(ws + oBs);
  float*    yb    = (float*)(ws + oYb);
  _Float16* Wa16B = (_Float16*)(ws + oWaB);
  float*    Wa0   = (float*)(ws + oWa0);
  _Float16* Xs16  = (_Float16*)(ws + oXs);
  _Float16* Mc    = (_Float16*)(ws + oMc);
  float*    vc    = (float*)(ws + oVc);
  _Float16* A_sl  = (_Float16*)(ws + oA);

  k_prep_wa<<<4096, 256, 0, stream>>>(Wa, Wa16B, Wa0);
  k_prep_x<<<4094, 256, 0, stream>>>(X, Xs16);
  k_y0<<<B_, 128, 0, stream>>>(X, Wi, bi, out, yb);
  k_bs<<<(B_ * T_ + 15) / 16, 256, 0, stream>>>(X, Wb, Bs);

  int nslices = NC / SC;
  int chunks = B_ * SC;
  int amat_gx = (B_ * SC * L_) / 64;
  for (int si = 0; si < nslices; si++) {
    int c0 = si * SC;
    k_amat<<<dim3(amat_gx, 128), 256, 0, stream>>>(Xs16, Wa16B, Wa0, A_sl, c0, scShift);
    k_compose<<<4 * chunks, 256, 0, stream>>>(A_sl, Bs, Mc, vc, c0, scShift);
    k_chainscan<<<B_, 256, 0, stream>>>(Mc, vc, yb, c0, scShift);
    k_emit<<<chunks, 256, 0, stream>>>(A_sl, Bs, yb, out, c0, scShift);
  }
}